// Round 6
// baseline (3480.055 us; speedup 1.0000x reference)
//
#include <hip/hip_runtime.h>

#define B 4
#define N 8192
#define F 64
#define S 2048
#define K 16
#define C 128
#define R (B*S*K)   // 131072 rows

// ---------- exact-arithmetic helpers (match numpy op order, no fma fusion) ----------
__device__ __forceinline__ float norm2f(float x, float y, float z) {
#pragma clang fp contract(off)
  return (x*x + y*y) + z*z;
}

__device__ __forceinline__ float dist2_sub(float ax, float ay, float az,
                                           float bx, float by, float bz) {
#pragma clang fp contract(off)
  float dx = ax - bx, dy = ay - by, dz = az - bz;
  return (dx*dx + dy*dy) + dz*dz;          // ((d0+d1)+d2), separate rounding
}

__device__ __forceinline__ float knn_d2(float4 q, float4 p) {
#pragma clang fp contract(off)
  float dot = (q.x*p.x + q.y*p.y) + q.z*p.z;
  return (q.w + p.w) - 2.0f*dot;           // (qn+pn) - 2*dot, reference order
}

// ---------- DPP cross-lane (VALU pipe). bound_ctrl=1 -> invalid lanes read 0:
// identity-safe for f32-max of nonneg and u32-max. Pattern HW-verified (rounds 2-5).
#define DPP_F(v, ctrl) __int_as_float(__builtin_amdgcn_update_dpp(0, __float_as_int(v), ctrl, 0xf, 0xf, true))
#define DPP_U(v, ctrl) ((unsigned)__builtin_amdgcn_update_dpp(0, (int)(v), ctrl, 0xf, 0xf, true))
__device__ __forceinline__ unsigned umaxu(unsigned a, unsigned b) { return a > b ? a : b; }

#define WAVE_MAX_F(x) do { \
  x = fmaxf(x, DPP_F(x,0x111)); x = fmaxf(x, DPP_F(x,0x112)); \
  x = fmaxf(x, DPP_F(x,0x114)); x = fmaxf(x, DPP_F(x,0x118)); \
  x = fmaxf(x, DPP_F(x,0x142)); x = fmaxf(x, DPP_F(x,0x143)); } while(0)

#define WAVE_MAX_U(x) do { \
  x = umaxu(x, DPP_U(x,0x111)); x = umaxu(x, DPP_U(x,0x112)); \
  x = umaxu(x, DPP_U(x,0x114)); x = umaxu(x, DPP_U(x,0x118)); \
  x = umaxu(x, DPP_U(x,0x142)); x = umaxu(x, DPP_U(x,0x143)); } while(0)

// lexicographic (value desc, key desc) pair-max over 16-lane rows (row_shr stages)
#define TAIL_STAGE(v, kk, ctrl) do { \
  float v2_ = DPP_F(v, ctrl); unsigned k2_ = DPP_U(kk, ctrl); \
  bool tk_ = (v2_ > v) || ((v2_ == v) & (k2_ > kk)); \
  v = tk_ ? v2_ : v; kk = tk_ ? k2_ : kk; } while(0)

// 6-bit/axis Morton interleave (18 bits)
__device__ __forceinline__ unsigned mort6(int qx, int qy, int qz) {
  unsigned m = 0;
#pragma unroll
  for (int b = 0; b < 6; ++b) {
    m |= ((unsigned)((qx>>b)&1) << (3*b+2))
       | ((unsigned)((qy>>b)&1) << (3*b+1))
       | ((unsigned)((qz>>b)&1) << (3*b+0));
  }
  return m;
}

// ---------- prep: pad xyz to float4 with |p|^2 in w ----------
__global__ void prep_kernel(const float* __restrict__ xyz, float4* __restrict__ pts4) {
  int i = blockIdx.x*blockDim.x + threadIdx.x;   // B*N
  if (i >= B*N) return;
  float x = xyz[i*3+0], y = xyz[i*3+1], z = xyz[i*3+2];
  pts4[i] = make_float4(x, y, z, norm2f(x, y, z));
}

// ---------- transpose w1 [o][c] -> w1t [c][o] for contiguous scalar weight loads ----------
__global__ void transpose_w1_kernel(const float* __restrict__ w1, float* __restrict__ w1t) {
  int i = blockIdx.x*256 + threadIdx.x;    // C*C = 16384
  int o = i >> 7, c = i & 127;
  w1t[c*C + o] = w1[o*C + c];
}

// ---------- FPS: 1024 threads/block, one block per batch. EXACT lazy update:
// Morton-clustered ownership (8 contiguous pts/thread), per-lane bounding spheres,
// wave-level ballot skip with cached (max, argmax-key). Selection is bit-exact:
// skips are provably identity updates; ties -> lowest original index via keys. ----------
__global__ __launch_bounds__(1024, 4) void fps_kernel(const float4* __restrict__ pts4,
                                                      float4* __restrict__ q4,
                                                      float* __restrict__ out_xyz) {
  const int b = blockIdx.x;
  const int t = threadIdx.x;               // 0..1023
  const float4* pb = pts4 + b*N;

  __shared__ float cx[N], cy[N], cz[N];    // 96 KB coords by ORIGINAL index
  __shared__ unsigned skey[N];             // 32 KB (morton<<13 | idx) sort keys
  __shared__ float sqx[S], sqy[S], sqz[S]; // 24 KB winner sequence
  __shared__ float    swv[2][16];
  __shared__ unsigned swk[2][16];

  // ---- stage coords to LDS + build Morton keys ----
#pragma unroll
  for (int j = 0; j < 8; ++j) {
    int i = j*1024 + t;
    float4 v = pb[i];                      // coalesced
    cx[i] = v.x; cy[i] = v.y; cz[i] = v.z;
    int qx = (int)((v.x + 6.0f) * (64.0f/12.0f));
    int qy = (int)((v.y + 6.0f) * (64.0f/12.0f));
    int qz = (int)((v.z + 6.0f) * (64.0f/12.0f));
    qx = min(max(qx,0),63); qy = min(max(qy,0),63); qz = min(max(qz,0),63);
    skey[i] = (mort6(qx,qy,qz) << 13) | (unsigned)i;
  }
  __syncthreads();

  // ---- in-LDS bitonic sort (ascending). Sort quality affects SPEED only. ----
  for (unsigned k = 2; k <= (unsigned)N; k <<= 1) {
    for (unsigned j = k >> 1; j > 0; j >>= 1) {
#pragma unroll
      for (int m = 0; m < 8; ++m) {
        int i = m*1024 + t;
        int ixj = i ^ (int)j;
        if (ixj > i) {
          unsigned a = skey[i], c2 = skey[ixj];
          bool up = ((i & (int)k) == 0);
          if ((a > c2) == up) { skey[i] = c2; skey[ixj] = a; }
        }
      }
      __syncthreads();
    }
  }

  // ---- ownership: thread owns 8 Morton-contiguous points; build sphere ----
  float ppx[8], ppy[8], ppz[8], md8[8]; int oi8[8];
#pragma unroll
  for (int c = 0; c < 8; ++c) {
    int o = (int)(skey[t*8 + c] & 0x1FFFu);
    oi8[c] = o;
    ppx[c] = cx[o]; ppy[c] = cy[o]; ppz[c] = cz[o];
    md8[c] = 1e10f;                        // BIG
  }
  float cxm = 0.f, cym = 0.f, czm = 0.f;
#pragma unroll
  for (int c = 0; c < 8; ++c) { cxm += ppx[c]; cym += ppy[c]; czm += ppz[c]; }
  cxm *= 0.125f; cym *= 0.125f; czm *= 0.125f;
  float r2 = 0.f;
#pragma unroll
  for (int c = 0; c < 8; ++c) {
    float dx = ppx[c]-cxm, dy = ppy[c]-cym, dz = ppz[c]-czm;
    r2 = fmaxf(r2, dx*dx + dy*dy + dz*dz);
  }
  const float r_up = sqrtf(r2) * 1.0001f + 1e-12f;   // conservative upper bound

  // ---- serial FPS loop ----
  float wx = cx[0], wy = cy[0], wz = cz[0];          // reference starts at idx 0
  float rvP = 0.f; unsigned kmP = 0u;                // per-wave cache (lane 63 valid)
  float sub = 1e19f;                                 // sqrt(ub) upper bound, huge init

  for (int s = 0; ; ++s) {
    if (t == 0) { sqx[s] = wx; sqy[s] = wy; sqz[s] = wz; }
    if (s == S-1) break;

    // exact skip test: if ||c-w|| >= r + sqrt(ub) (with margins), update is identity
    float dcx = cxm - wx, dcy = cym - wy, dcz = czm - wz;
    float D = dcx*dcx + dcy*dcy + dcz*dcz;
    bool can_skip = (sqrtf(D) * 0.9999f) >= (r_up + sub) * 1.0001f;
    if (__ballot(can_skip) != ~0ull) {
      // update 8 points + per-lane lexicographic argmax (max md, tie -> min orig idx)
      float bv = -1.0f; int boi = 0x7FFFFFFF;
#pragma unroll
      for (int c = 0; c < 8; ++c) {
        float d = dist2_sub(ppx[c], ppy[c], ppz[c], wx, wy, wz);
        float m = fminf(md8[c], d);
        md8[c] = m;
        bool g = (m > bv) || ((m == bv) & (oi8[c] < boi));
        bv  = g ? m      : bv;
        boi = g ? oi8[c] : boi;
      }
      float rv = bv;
      WAVE_MAX_F(rv);                      // lane 63: wave-exact max
      float bwu = __int_as_float(__builtin_amdgcn_readlane(__float_as_int(rv), 63));
      unsigned ki = (bv == bwu) ? (0x7FFFFFFFu - (unsigned)boi) : 0u;
      WAVE_MAX_U(ki);                      // lane 63: max key = min orig idx at max
      rvP = rv; kmP = ki;
      sub = sqrtf(bwu) * 1.0001f;          // new ub bound for skip test
    }
    int par = s & 1;
    if ((t & 63) == 63) { swv[par][t >> 6] = rvP; swk[par][t >> 6] = kmP; }
    __syncthreads();                       // parity dbuf -> single barrier/step

    // block tail-reduce over 16 wave entries: lane-parallel + 4 DPP stages
    float    v  = swv[par][t & 15];
    unsigned kk = swk[par][t & 15];
    TAIL_STAGE(v, kk, 0x111);
    TAIL_STAGE(v, kk, 0x112);
    TAIL_STAGE(v, kk, 0x114);
    TAIL_STAGE(v, kk, 0x118);              // lane 15 of each 16-row = block result
    unsigned kb = (unsigned)__builtin_amdgcn_readlane((int)kk, 63);
    int w = (int)(0x7FFFFFFFu - kb);       // winner original index
    wx = cx[w]; wy = cy[w]; wz = cz[w];    // same-address LDS broadcast
  }

  __syncthreads();                         // seq complete
  for (int i = t; i < S; i += 1024) {
    float x = sqx[i], y = sqy[i], z = sqz[i];
    q4[b*S + i] = make_float4(x, y, z, norm2f(x, y, z));
    out_xyz[(b*S + i)*3 + 0] = x;
    out_xyz[(b*S + i)*3 + 1] = y;
    out_xyz[(b*S + i)*3 + 2] = z;
  }
}

// ---------- KNN: one WAVE per query; per-lane sorted top-16 over 128 points,
// then exact 16-round DPP extraction merge (min d, tie -> min point index) ----------
__global__ __launch_bounds__(256, 4) void knn_kernel(const float4* __restrict__ pts4,
                                                     const float4* __restrict__ q4,
                                                     int* __restrict__ knn) {
  const int gtid = blockIdx.x*256 + threadIdx.x;
  const int wave = gtid >> 6;              // query id, 0..B*S-1
  const int lane = threadIdx.x & 63;
  const int b = wave >> 11;                // S = 2048
  const float4* pb = pts4 + (size_t)b*N;
  float4 q = q4[wave];                     // same addr across wave -> broadcast

  float dv[16]; int di[16];
#pragma unroll
  for (int j = 0; j < 16; ++j) { dv[j] = 3.4e38f; di[j] = 0x7FFFFFFF; }

  // scan: lane owns points n = j*64 + lane (ascending -> within-lane ties keep lower idx)
  for (int j = 0; j < N/64; ++j) {
    int n = j*64 + lane;
    float4 p = pb[n];                      // coalesced global_load_dwordx4
    float d2 = knn_d2(q, p);
#pragma unroll
    for (int k = 15; k >= 1; --k) {
      bool s1 = d2 < dv[k-1];              // strict: incumbent (earlier idx) wins ties
      bool s2 = d2 < dv[k];
      dv[k] = fmaxf(dv[k-1], fminf(d2, dv[k]));   // med3: sorted-insert value update
      di[k] = s1 ? di[k-1] : (s2 ? n : di[k]);
    }
    bool s0 = d2 < dv[0];
    dv[0] = fminf(d2, dv[0]);
    di[0] = s0 ? n : di[0];
  }

  // merge: 16 extraction rounds over the 64 sorted lane-lists
  int myg = 0;
#pragma unroll 1
  for (int r = 0; r < 16; ++r) {
    unsigned bits = __float_as_uint(dv[0]);
    unsigned ord  = bits ^ (0x80000000u | (unsigned)(((int)bits) >> 31));
    unsigned mk   = ~ord;                  // max(mk) == min distance (total order)
    unsigned m = mk;
    WAVE_MAX_U(m);
    unsigned wm = (unsigned)__builtin_amdgcn_readlane((int)m, 63);
    unsigned ci = (mk == wm) ? ~(unsigned)di[0] : 0u;
    unsigned m2 = ci;
    WAVE_MAX_U(m2);
    unsigned wi = (unsigned)__builtin_amdgcn_readlane((int)m2, 63);
    int g = (int)~wi;                      // winning global point index
    if (lane == r) myg = g;
    bool win = (mk == wm) && ((unsigned)di[0] == ~wi);
#pragma unroll
    for (int k = 0; k < 15; ++k) {
      dv[k] = win ? dv[k+1] : dv[k];
      di[k] = win ? di[k+1] : di[k];
    }
    dv[15] = win ? 3.4e38f    : dv[15];
    di[15] = win ? 0x7FFFFFFF : di[15];
  }
  if (lane < 16) knn[wave*16 + lane] = myg;   // coalesced 16-wide store
}

// ---------- GEMM0: gather row (3 xyz-norm + 64 feat) and multiply by w0 [128x67] ----------
__global__ __launch_bounds__(256, 2) void gemm0_kernel(const float4* __restrict__ pts4,
                                                       const float4* __restrict__ q4,
                                                       const float* __restrict__ feat,
                                                       const int* __restrict__ knn,
                                                       const float* __restrict__ w0,
                                                       const float* __restrict__ b0,
                                                       float* __restrict__ Z) {
  int r = blockIdx.x*256 + threadIdx.x;    // 0..R-1
  int bs = r >> 4;                         // b*S + s
  int b  = r >> 15;                        // S*K = 32768 rows per batch
  int p  = knn[r];
  float4 q  = q4[bs];
  float4 pp = pts4[b*N + p];

  float row[67];
  row[0] = pp.x - q.x; row[1] = pp.y - q.y; row[2] = pp.z - q.z;
  const float4* fp = (const float4*)(feat + (size_t)(b*N + p)*F);
#pragma unroll
  for (int i = 0; i < 16; ++i) {
    float4 v = fp[i];
    row[3+4*i] = v.x; row[4+4*i] = v.y; row[5+4*i] = v.z; row[6+4*i] = v.w;
  }

  float* zr = Z + (size_t)r*C;
  for (int og = 0; og < C/4; ++og) {
    float a0 = b0[og*4+0], a1 = b0[og*4+1], a2 = b0[og*4+2], a3 = b0[og*4+3];
    const float* wr = w0 + og*4*67;        // uniform -> scalar loads
#pragma unroll
    for (int c = 0; c < 67; ++c) {
      float x = row[c];
      a0 = fmaf(x, wr[c      ], a0);
      a1 = fmaf(x, wr[67  + c], a1);
      a2 = fmaf(x, wr[134 + c], a2);
      a3 = fmaf(x, wr[201 + c], a3);
    }
    ((float4*)zr)[og] = make_float4(a0, a1, a2, a3);
  }
}

// ---------- per-channel stats partials: sum and sumsq over rows ----------
__global__ void stats_kernel(const float* __restrict__ Z, float* __restrict__ part) {
  int c = threadIdx.x & 127;
  int g = threadIdx.x >> 7;                // 0/1
  int chunk = blockIdx.x*2 + g;            // 0..255
  const int rows = R/256;                  // 512
  const float* zp = Z + (size_t)chunk*rows*C + c;
  float s1 = 0.f, s2 = 0.f;
  for (int j = 0; j < rows; ++j) {
    float v = zp[(size_t)j*C];
    s1 += v;
    s2 = fmaf(v, v, s2);
  }
  __shared__ float sh[2][2][128];
  sh[g][0][c] = s1; sh[g][1][c] = s2;
  __syncthreads();
  if (g == 0) {
    part[(blockIdx.x*128 + c)*2 + 0] = s1 + sh[1][0][c];
    part[(blockIdx.x*128 + c)*2 + 1] = s2 + sh[1][1][c];
  }
}

// ---------- finalize BN: A = gamma*rstd, B = beta - mean*gamma*rstd ----------
__global__ void finalize_kernel(const float* __restrict__ part,
                                const float* __restrict__ gamma,
                                const float* __restrict__ beta,
                                float* __restrict__ AB) {
  int c = threadIdx.x;                     // 128 threads
  float s1 = 0.f, s2 = 0.f;
  for (int i = 0; i < 128; ++i) {
    s1 += part[(i*128 + c)*2 + 0];
    s2 += part[(i*128 + c)*2 + 1];
  }
  const float inv = 1.0f/(float)R;
  float mean = s1*inv;
  float var  = s2*inv - mean*mean;         // biased variance
  float rstd = rsqrtf(var + 1e-5f);
  float a = gamma[c]*rstd;
  AB[c]     = a;
  AB[C + c] = beta[c] - mean*a;
}

// ---------- GEMM1: LDS-tiled (64 rows/block), no register spill, in-place on Z ----------
__global__ __launch_bounds__(256, 4) void gemm1_kernel(float* __restrict__ Z,
                                                       const float* __restrict__ AB0,
                                                       const float* __restrict__ w1t,
                                                       const float* __restrict__ b1) {
  __shared__ float hs[64 * 129];           // stride 129: 2-way bank aliasing = free
  const int tid = threadIdx.x;
  const size_t base = (size_t)blockIdx.x * 64;

  const float4* Z4 = (const float4*)(Z + base * C);
#pragma unroll
  for (int k = 0; k < 8; ++k) {
    int f = tid + k*256;                   // float4 index, 0..2047
    int row = f >> 5, c4 = f & 31;
    float4 v  = Z4[f];
    float4 A  = ((const float4*)AB0)[c4];
    float4 Bb = ((const float4*)AB0)[32 + c4];
    int lb = row*129 + c4*4;
    hs[lb+0] = fmaxf(fmaf(v.x, A.x, Bb.x), 0.f);
    hs[lb+1] = fmaxf(fmaf(v.y, A.y, Bb.y), 0.f);
    hs[lb+2] = fmaxf(fmaf(v.z, A.z, Bb.z), 0.f);
    hs[lb+3] = fmaxf(fmaf(v.w, A.w, Bb.w), 0.f);
  }
  __syncthreads();

  const int row = tid & 63;
  const int qu  = __builtin_amdgcn_readfirstlane(tid >> 6);  // wave-uniform -> s_loads
  const float* wq = w1t + qu*32;           // w1t[c*C + o]
  float acc[32];
#pragma unroll
  for (int o = 0; o < 32; ++o) acc[o] = b1[qu*32 + o];
  const float* hrow = hs + row*129;
  for (int c = 0; c < C; ++c) {
    float x = hrow[c];
    const float* wr = wq + c*C;            // uniform: s_load_dwordx16 x2
#pragma unroll
    for (int o = 0; o < 32; ++o) acc[o] = fmaf(x, wr[o], acc[o]);
  }
  __syncthreads();

#pragma unroll
  for (int o = 0; o < 32; ++o) hs[row*129 + qu*32 + o] = acc[o];
  __syncthreads();
  float4* Zo = (float4*)(Z + base * C);
#pragma unroll
  for (int k = 0; k < 8; ++k) {
    int f = tid + k*256;
    int row2 = f >> 5, c4 = f & 31;
    int lb = row2*129 + c4*4;
    Zo[f] = make_float4(hs[lb+0], hs[lb+1], hs[lb+2], hs[lb+3]);
  }
}

// ---------- maxpool over K with BN1+ReLU fused ----------
__global__ void maxpool_kernel(const float* __restrict__ Z,
                               const float* __restrict__ AB1,
                               float* __restrict__ outF) {
  int t = blockIdx.x*256 + threadIdx.x;    // B*S*32
  int bs = t >> 5, c4 = t & 31;
  const float4* zp = (const float4*)Z + (size_t)bs*K*(C/4) + c4;
  float4 A  = ((const float4*)AB1)[c4];
  float4 Bb = ((const float4*)(AB1 + C))[c4];
  float4 m = make_float4(-3.4e38f, -3.4e38f, -3.4e38f, -3.4e38f);
#pragma unroll
  for (int k = 0; k < K; ++k) {
    float4 z = zp[(size_t)k*(C/4)];
    m.x = fmaxf(m.x, fmaf(z.x, A.x, Bb.x));
    m.y = fmaxf(m.y, fmaf(z.y, A.y, Bb.y));
    m.z = fmaxf(m.z, fmaf(z.z, A.z, Bb.z));
    m.w = fmaxf(m.w, fmaf(z.w, A.w, Bb.w));
  }
  m.x = fmaxf(m.x, 0.f); m.y = fmaxf(m.y, 0.f);
  m.z = fmaxf(m.z, 0.f); m.w = fmaxf(m.w, 0.f);
  ((float4*)outF)[t] = m;                  // max(relu(x)) == relu(max(x))
}

extern "C" void kernel_launch(void* const* d_in, const int* in_sizes, int n_in,
                              void* d_out, int out_size, void* d_ws, size_t ws_size,
                              hipStream_t stream) {
  const float* xyz      = (const float*)d_in[0];
  const float* features = (const float*)d_in[1];
  const float* w0  = (const float*)d_in[2];
  const float* b0  = (const float*)d_in[3];
  const float* g0  = (const float*)d_in[4];
  const float* be0 = (const float*)d_in[5];
  const float* w1  = (const float*)d_in[6];
  const float* b1  = (const float*)d_in[7];
  const float* g1  = (const float*)d_in[8];
  const float* be1 = (const float*)d_in[9];

  char* wp = (char*)d_ws;
  float4* pts4 = (float4*)wp;  wp += (size_t)B*N*sizeof(float4);     // 512 KB
  float4* q4   = (float4*)wp;  wp += (size_t)B*S*sizeof(float4);     // 128 KB
  int*    knn  = (int*)wp;     wp += (size_t)R*sizeof(int);          // 512 KB
  float*  Z    = (float*)wp;   wp += (size_t)R*C*sizeof(float);      // 64 MB
  float*  part = (float*)wp;   wp += (size_t)128*C*2*sizeof(float);  // 128 KB
  float*  AB0  = (float*)wp;   wp += (size_t)2*C*sizeof(float);
  float*  AB1  = (float*)wp;   wp += (size_t)2*C*sizeof(float);
  float*  w1t  = (float*)wp;   wp += (size_t)C*C*sizeof(float);      // 64 KB

  float* out_xyz  = (float*)d_out;            // [B,S,3]
  float* out_feat = (float*)d_out + B*S*3;    // [B,S,C]

  prep_kernel<<<(B*N)/256, 256, 0, stream>>>(xyz, pts4);
  transpose_w1_kernel<<<(C*C)/256, 256, 0, stream>>>(w1, w1t);
  fps_kernel<<<B, 1024, 0, stream>>>(pts4, q4, out_xyz);
  knn_kernel<<<(B*S*64)/256, 256, 0, stream>>>(pts4, q4, knn);
  gemm0_kernel<<<R/256, 256, 0, stream>>>(pts4, q4, features, knn, w0, b0, Z);
  stats_kernel<<<128, 256, 0, stream>>>(Z, part);
  finalize_kernel<<<1, 128, 0, stream>>>(part, g0, be0, AB0);
  gemm1_kernel<<<R/64, 256, 0, stream>>>(Z, AB0, w1t, b1);
  stats_kernel<<<128, 256, 0, stream>>>(Z, part);
  finalize_kernel<<<1, 128, 0, stream>>>(part, g1, be1, AB1);
  maxpool_kernel<<<(B*S*32)/256, 256, 0, stream>>>(Z, AB1, out_feat);
}

// Round 7
// 2476.798 us; speedup vs baseline: 1.4051x; 1.4051x over previous
//
#include <hip/hip_runtime.h>

#define B 4
#define N 8192
#define F 64
#define S 2048
#define K 16
#define C 128
#define R (B*S*K)   // 131072 rows

typedef float v2f __attribute__((ext_vector_type(2)));

// ---------- exact-arithmetic helpers (match numpy op order, no fma fusion) ----------
__device__ __forceinline__ float norm2f(float x, float y, float z) {
#pragma clang fp contract(off)
  return (x*x + y*y) + z*z;
}

__device__ __forceinline__ float knn_d2(float4 q, float4 p) {
#pragma clang fp contract(off)
  float dot = (q.x*p.x + q.y*p.y) + q.z*p.z;
  return (q.w + p.w) - 2.0f*dot;           // (qn+pn) - 2*dot, reference order
}

// opaque def: forbids rematerialization/LICM of the loaded value -> stays in a VGPR
__device__ __forceinline__ void pinf(float& v) { asm volatile("" : "+v"(v)); }

// ---------- DPP cross-lane (VALU pipe). bound_ctrl=1 -> invalid lanes read 0:
// identity-safe for f32-max of nonneg and u32-max. Pattern HW-verified (rounds 2-6).
#define DPP_F(v, ctrl) __int_as_float(__builtin_amdgcn_update_dpp(0, __float_as_int(v), ctrl, 0xf, 0xf, true))
#define DPP_U(v, ctrl) ((unsigned)__builtin_amdgcn_update_dpp(0, (int)(v), ctrl, 0xf, 0xf, true))
__device__ __forceinline__ unsigned umaxu(unsigned a, unsigned b) { return a > b ? a : b; }

#define WAVE_MAX_F(x) do { \
  x = fmaxf(x, DPP_F(x,0x111)); x = fmaxf(x, DPP_F(x,0x112)); \
  x = fmaxf(x, DPP_F(x,0x114)); x = fmaxf(x, DPP_F(x,0x118)); \
  x = fmaxf(x, DPP_F(x,0x142)); x = fmaxf(x, DPP_F(x,0x143)); } while(0)

#define WAVE_MAX_U(x) do { \
  x = umaxu(x, DPP_U(x,0x111)); x = umaxu(x, DPP_U(x,0x112)); \
  x = umaxu(x, DPP_U(x,0x114)); x = umaxu(x, DPP_U(x,0x118)); \
  x = umaxu(x, DPP_U(x,0x142)); x = umaxu(x, DPP_U(x,0x143)); } while(0)

// ---------- prep: pad xyz to float4 with |p|^2 in w ----------
__global__ void prep_kernel(const float* __restrict__ xyz, float4* __restrict__ pts4) {
  int i = blockIdx.x*blockDim.x + threadIdx.x;   // B*N
  if (i >= B*N) return;
  float x = xyz[i*3+0], y = xyz[i*3+1], z = xyz[i*3+2];
  pts4[i] = make_float4(x, y, z, norm2f(x, y, z));
}

// ---------- transpose w1 [o][c] -> w1t [c][o] for contiguous scalar weight loads ----------
__global__ void transpose_w1_kernel(const float* __restrict__ w1, float* __restrict__ w1t) {
  int i = blockIdx.x*256 + threadIdx.x;    // C*C = 16384
  int o = i >> 7, c = i & 127;
  w1t[c*C + o] = w1[o*C + c];
}

// ---------- FPS: one block per batch, 256 threads. Round-5 structure (known good):
// points pinned in VGPRs, LDS winner buffer, single barrier/step.
// New: explicit v2f packed math (v_pk_*_f32), split argmax chains, float4 winner cache. ----------
__global__ __launch_bounds__(256, 1) void fps_kernel(const float4* __restrict__ pts4,
                                                     float4* __restrict__ q4,
                                                     float* __restrict__ out_xyz) {
  const int b = blockIdx.x;
  const int t = threadIdx.x;
  const int wid = t >> 6;
  const float4* pb = pts4 + b*N;

  __shared__ float4 cw[N];                 // 128 KB point cache (winner lookup, b128 read)
  __shared__ float sqx[S], sqy[S], sqz[S]; // 24 KB winner sequence
  __shared__ float    swv[2][4];
  __shared__ unsigned swk[2][4];

  // thread t owns points i*256+t, i=0..31, paired (2j, 2j+1); pinned in VGPRs
  v2f px[16], py[16], pz[16], md[16];
#pragma unroll
  for (int j = 0; j < 16; ++j) {
    int i0 = (2*j)*256 + t, i1 = (2*j+1)*256 + t;
    float4 v0 = pb[i0];                    // coalesced
    float4 v1 = pb[i1];
    cw[i0] = v0; cw[i1] = v1;
    pinf(v0.x); pinf(v0.y); pinf(v0.z);
    pinf(v1.x); pinf(v1.y); pinf(v1.z);
    px[j] = (v2f){v0.x, v1.x};
    py[j] = (v2f){v0.y, v1.y};
    pz[j] = (v2f){v0.z, v1.z};
    md[j] = (v2f){1e10f, 1e10f};           // BIG
  }

  float wx, wy, wz;
  { float4 p0 = pb[0]; wx = p0.x; wy = p0.y; wz = p0.z; }  // reference starts at idx 0
  const unsigned cbt = 0x7FFFFFFFu - (unsigned)t;          // complement of global idx base

  for (int s = 0; ; ++s) {
    if (t == 0) { sqx[s] = wx; sqy[s] = wy; sqz[s] = wz; }
    if (s == S-1) break;

    // packed min_d update + two independent argmax chains (slots 0..15 / 16..31).
    // per-element IEEE rounding identical to scalar ((dx*dx+dy*dy)+dz*dz).
    v2f wxx = (v2f){wx, wx}, wyy = (v2f){wy, wy}, wzz = (v2f){wz, wz};
    float bvA = -1.0f, bvB = -1.0f; int biA = 0, biB = 0;
#pragma unroll
    for (int j = 0; j < 16; ++j) {
#pragma clang fp contract(off)
      v2f dx = px[j] - wxx;
      v2f dy = py[j] - wyy;
      v2f dz = pz[j] - wzz;
      v2f d  = (dx*dx + dy*dy) + dz*dz;    // v_pk_sub/mul/add, no fma
      v2f m;
      m.x = fminf(md[j].x, d.x);
      m.y = fminf(md[j].y, d.y);
      md[j] = m;
      if (j < 8) {                         // chain A: slots 0..15
        bool g0 = m.x > bvA;  bvA = g0 ? m.x : bvA;  biA = g0 ? (2*j)   : biA;
        bool g1 = m.y > bvA;  bvA = g1 ? m.y : bvA;  biA = g1 ? (2*j+1) : biA;
      } else {                             // chain B: slots 16..31
        bool g0 = m.x > bvB;  bvB = g0 ? m.x : bvB;  biB = g0 ? (2*j)   : biB;
        bool g1 = m.y > bvB;  bvB = g1 ? m.y : bvB;  biB = g1 ? (2*j+1) : biB;
      }
    }
    // merge chains: strict > keeps A (lower slots = lower global idx) on ties
    bool gB = bvB > bvA;
    float bv = gB ? bvB : bvA;
    int   bi = gB ? biB : biA;

    // wave-exact max, then min-global-index key among lanes attaining it
    float rv = bv;
    WAVE_MAX_F(rv);
    float bwu = __int_as_float(__builtin_amdgcn_readlane(__float_as_int(rv), 63));
    unsigned ki = (bv == bwu) ? (cbt - ((unsigned)bi << 8)) : 0u;  // 0x7FFFFFFF - (bi*256+t)
    unsigned km = ki;
    WAVE_MAX_U(km);

    int par = s & 1;
    if ((t & 63) == 63) { swv[par][wid] = rv; swk[par][wid] = km; }
    __syncthreads();                       // only lgkm to drain: cheap

    float v0 = swv[par][0], v1 = swv[par][1], v2 = swv[par][2], v3 = swv[par][3];
    float bm = fmaxf(fmaxf(v0, v1), fmaxf(v2, v3));        // exact block max
    unsigned c0 = (v0 == bm) ? swk[par][0] : 0u;
    unsigned c1 = (v1 == bm) ? swk[par][1] : 0u;
    unsigned c2 = (v2 == bm) ? swk[par][2] : 0u;
    unsigned c3 = (v3 == bm) ? swk[par][3] : 0u;
    unsigned kb = umaxu(umaxu(c0, c1), umaxu(c2, c3));     // min global idx at bm
    int w = (int)(0x7FFFFFFFu - kb);
    float4 pw = cw[w];                     // one same-address ds_read_b128 broadcast
    wx = pw.x; wy = pw.y; wz = pw.z;
  }

  __syncthreads();                         // seq complete
#pragma unroll
  for (int i = t; i < S; i += 256) {
    float x = sqx[i], y = sqy[i], z = sqz[i];
    q4[b*S + i] = make_float4(x, y, z, norm2f(x, y, z));
    out_xyz[(b*S + i)*3 + 0] = x;
    out_xyz[(b*S + i)*3 + 1] = y;
    out_xyz[(b*S + i)*3 + 2] = z;
  }
}

// ---------- KNN: one WAVE per query; per-lane sorted top-16 over 128 points,
// then exact 16-round DPP extraction merge (min d, tie -> min point index) ----------
__global__ __launch_bounds__(256, 4) void knn_kernel(const float4* __restrict__ pts4,
                                                     const float4* __restrict__ q4,
                                                     int* __restrict__ knn) {
  const int gtid = blockIdx.x*256 + threadIdx.x;
  const int wave = gtid >> 6;              // query id, 0..B*S-1
  const int lane = threadIdx.x & 63;
  const int b = wave >> 11;                // S = 2048
  const float4* pb = pts4 + (size_t)b*N;
  float4 q = q4[wave];                     // same addr across wave -> broadcast

  float dv[16]; int di[16];
#pragma unroll
  for (int j = 0; j < 16; ++j) { dv[j] = 3.4e38f; di[j] = 0x7FFFFFFF; }

  // scan: lane owns points n = j*64 + lane (ascending -> within-lane ties keep lower idx)
  for (int j = 0; j < N/64; ++j) {
    int n = j*64 + lane;
    float4 p = pb[n];                      // coalesced global_load_dwordx4
    float d2 = knn_d2(q, p);
#pragma unroll
    for (int k = 15; k >= 1; --k) {
      bool s1 = d2 < dv[k-1];              // strict: incumbent (earlier idx) wins ties
      bool s2 = d2 < dv[k];
      dv[k] = fmaxf(dv[k-1], fminf(d2, dv[k]));   // med3: sorted-insert value update
      di[k] = s1 ? di[k-1] : (s2 ? n : di[k]);
    }
    bool s0 = d2 < dv[0];
    dv[0] = fminf(d2, dv[0]);
    di[0] = s0 ? n : di[0];
  }

  // merge: 16 extraction rounds over the 64 sorted lane-lists
  int myg = 0;
#pragma unroll 1
  for (int r = 0; r < 16; ++r) {
    unsigned bits = __float_as_uint(dv[0]);
    unsigned ord  = bits ^ (0x80000000u | (unsigned)(((int)bits) >> 31));
    unsigned mk   = ~ord;                  // max(mk) == min distance (total order)
    unsigned m = mk;
    WAVE_MAX_U(m);
    unsigned wm = (unsigned)__builtin_amdgcn_readlane((int)m, 63);
    unsigned ci = (mk == wm) ? ~(unsigned)di[0] : 0u;
    unsigned m2 = ci;
    WAVE_MAX_U(m2);
    unsigned wi = (unsigned)__builtin_amdgcn_readlane((int)m2, 63);
    int g = (int)~wi;                      // winning global point index
    if (lane == r) myg = g;
    bool win = (mk == wm) && ((unsigned)di[0] == ~wi);
#pragma unroll
    for (int k = 0; k < 15; ++k) {
      dv[k] = win ? dv[k+1] : dv[k];
      di[k] = win ? di[k+1] : di[k];
    }
    dv[15] = win ? 3.4e38f    : dv[15];
    di[15] = win ? 0x7FFFFFFF : di[15];
  }
  if (lane < 16) knn[wave*16 + lane] = myg;   // coalesced 16-wide store
}

// ---------- GEMM0: gather row (3 xyz-norm + 64 feat) and multiply by w0 [128x67] ----------
__global__ __launch_bounds__(256, 2) void gemm0_kernel(const float4* __restrict__ pts4,
                                                       const float4* __restrict__ q4,
                                                       const float* __restrict__ feat,
                                                       const int* __restrict__ knn,
                                                       const float* __restrict__ w0,
                                                       const float* __restrict__ b0,
                                                       float* __restrict__ Z) {
  int r = blockIdx.x*256 + threadIdx.x;    // 0..R-1
  int bs = r >> 4;                         // b*S + s
  int b  = r >> 15;                        // S*K = 32768 rows per batch
  int p  = knn[r];
  float4 q  = q4[bs];
  float4 pp = pts4[b*N + p];

  float row[67];
  row[0] = pp.x - q.x; row[1] = pp.y - q.y; row[2] = pp.z - q.z;
  const float4* fp = (const float4*)(feat + (size_t)(b*N + p)*F);
#pragma unroll
  for (int i = 0; i < 16; ++i) {
    float4 v = fp[i];
    row[3+4*i] = v.x; row[4+4*i] = v.y; row[5+4*i] = v.z; row[6+4*i] = v.w;
  }

  float* zr = Z + (size_t)r*C;
  for (int og = 0; og < C/4; ++og) {
    float a0 = b0[og*4+0], a1 = b0[og*4+1], a2 = b0[og*4+2], a3 = b0[og*4+3];
    const float* wr = w0 + og*4*67;        // uniform -> scalar loads
#pragma unroll
    for (int c = 0; c < 67; ++c) {
      float x = row[c];
      a0 = fmaf(x, wr[c      ], a0);
      a1 = fmaf(x, wr[67  + c], a1);
      a2 = fmaf(x, wr[134 + c], a2);
      a3 = fmaf(x, wr[201 + c], a3);
    }
    ((float4*)zr)[og] = make_float4(a0, a1, a2, a3);
  }
}

// ---------- per-channel stats partials: sum and sumsq over rows ----------
__global__ void stats_kernel(const float* __restrict__ Z, float* __restrict__ part) {
  int c = threadIdx.x & 127;
  int g = threadIdx.x >> 7;                // 0/1
  int chunk = blockIdx.x*2 + g;            // 0..255
  const int rows = R/256;                  // 512
  const float* zp = Z + (size_t)chunk*rows*C + c;
  float s1 = 0.f, s2 = 0.f;
  for (int j = 0; j < rows; ++j) {
    float v = zp[(size_t)j*C];
    s1 += v;
    s2 = fmaf(v, v, s2);
  }
  __shared__ float sh[2][2][128];
  sh[g][0][c] = s1; sh[g][1][c] = s2;
  __syncthreads();
  if (g == 0) {
    part[(blockIdx.x*128 + c)*2 + 0] = s1 + sh[1][0][c];
    part[(blockIdx.x*128 + c)*2 + 1] = s2 + sh[1][1][c];
  }
}

// ---------- finalize BN: A = gamma*rstd, B = beta - mean*gamma*rstd ----------
__global__ void finalize_kernel(const float* __restrict__ part,
                                const float* __restrict__ gamma,
                                const float* __restrict__ beta,
                                float* __restrict__ AB) {
  int c = threadIdx.x;                     // 128 threads
  float s1 = 0.f, s2 = 0.f;
  for (int i = 0; i < 128; ++i) {
    s1 += part[(i*128 + c)*2 + 0];
    s2 += part[(i*128 + c)*2 + 1];
  }
  const float inv = 1.0f/(float)R;
  float mean = s1*inv;
  float var  = s2*inv - mean*mean;         // biased variance
  float rstd = rsqrtf(var + 1e-5f);
  float a = gamma[c]*rstd;
  AB[c]     = a;
  AB[C + c] = beta[c] - mean*a;
}

// ---------- GEMM1: LDS-tiled (64 rows/block), no register spill, in-place on Z ----------
__global__ __launch_bounds__(256, 4) void gemm1_kernel(float* __restrict__ Z,
                                                       const float* __restrict__ AB0,
                                                       const float* __restrict__ w1t,
                                                       const float* __restrict__ b1) {
  __shared__ float hs[64 * 129];           // stride 129: 2-way bank aliasing = free
  const int tid = threadIdx.x;
  const size_t base = (size_t)blockIdx.x * 64;

  const float4* Z4 = (const float4*)(Z + base * C);
#pragma unroll
  for (int k = 0; k < 8; ++k) {
    int f = tid + k*256;                   // float4 index, 0..2047
    int row = f >> 5, c4 = f & 31;
    float4 v  = Z4[f];
    float4 A  = ((const float4*)AB0)[c4];
    float4 Bb = ((const float4*)AB0)[32 + c4];
    int lb = row*129 + c4*4;
    hs[lb+0] = fmaxf(fmaf(v.x, A.x, Bb.x), 0.f);
    hs[lb+1] = fmaxf(fmaf(v.y, A.y, Bb.y), 0.f);
    hs[lb+2] = fmaxf(fmaf(v.z, A.z, Bb.z), 0.f);
    hs[lb+3] = fmaxf(fmaf(v.w, A.w, Bb.w), 0.f);
  }
  __syncthreads();

  const int row = tid & 63;
  const int qu  = __builtin_amdgcn_readfirstlane(tid >> 6);  // wave-uniform -> s_loads
  const float* wq = w1t + qu*32;           // w1t[c*C + o]
  float acc[32];
#pragma unroll
  for (int o = 0; o < 32; ++o) acc[o] = b1[qu*32 + o];
  const float* hrow = hs + row*129;
  for (int c = 0; c < C; ++c) {
    float x = hrow[c];
    const float* wr = wq + c*C;            // uniform: s_load_dwordx16 x2
#pragma unroll
    for (int o = 0; o < 32; ++o) acc[o] = fmaf(x, wr[o], acc[o]);
  }
  __syncthreads();

#pragma unroll
  for (int o = 0; o < 32; ++o) hs[row*129 + qu*32 + o] = acc[o];
  __syncthreads();
  float4* Zo = (float4*)(Z + base * C);
#pragma unroll
  for (int k = 0; k < 8; ++k) {
    int f = tid + k*256;
    int row2 = f >> 5, c4 = f & 31;
    int lb = row2*129 + c4*4;
    Zo[f] = make_float4(hs[lb+0], hs[lb+1], hs[lb+2], hs[lb+3]);
  }
}

// ---------- maxpool over K with BN1+ReLU fused ----------
__global__ void maxpool_kernel(const float* __restrict__ Z,
                               const float* __restrict__ AB1,
                               float* __restrict__ outF) {
  int t = blockIdx.x*256 + threadIdx.x;    // B*S*32
  int bs = t >> 5, c4 = t & 31;
  const float4* zp = (const float4*)Z + (size_t)bs*K*(C/4) + c4;
  float4 A  = ((const float4*)AB1)[c4];
  float4 Bb = ((const float4*)(AB1 + C))[c4];
  float4 m = make_float4(-3.4e38f, -3.4e38f, -3.4e38f, -3.4e38f);
#pragma unroll
  for (int k = 0; k < K; ++k) {
    float4 z = zp[(size_t)k*(C/4)];
    m.x = fmaxf(m.x, fmaf(z.x, A.x, Bb.x));
    m.y = fmaxf(m.y, fmaf(z.y, A.y, Bb.y));
    m.z = fmaxf(m.z, fmaf(z.z, A.z, Bb.z));
    m.w = fmaxf(m.w, fmaf(z.w, A.w, Bb.w));
  }
  m.x = fmaxf(m.x, 0.f); m.y = fmaxf(m.y, 0.f);
  m.z = fmaxf(m.z, 0.f); m.w = fmaxf(m.w, 0.f);
  ((float4*)outF)[t] = m;                  // max(relu(x)) == relu(max(x))
}

extern "C" void kernel_launch(void* const* d_in, const int* in_sizes, int n_in,
                              void* d_out, int out_size, void* d_ws, size_t ws_size,
                              hipStream_t stream) {
  const float* xyz      = (const float*)d_in[0];
  const float* features = (const float*)d_in[1];
  const float* w0  = (const float*)d_in[2];
  const float* b0  = (const float*)d_in[3];
  const float* g0  = (const float*)d_in[4];
  const float* be0 = (const float*)d_in[5];
  const float* w1  = (const float*)d_in[6];
  const float* b1  = (const float*)d_in[7];
  const float* g1  = (const float*)d_in[8];
  const float* be1 = (const float*)d_in[9];

  char* wp = (char*)d_ws;
  float4* pts4 = (float4*)wp;  wp += (size_t)B*N*sizeof(float4);     // 512 KB
  float4* q4   = (float4*)wp;  wp += (size_t)B*S*sizeof(float4);     // 128 KB
  int*    knn  = (int*)wp;     wp += (size_t)R*sizeof(int);          // 512 KB
  float*  Z    = (float*)wp;   wp += (size_t)R*C*sizeof(float);      // 64 MB
  float*  part = (float*)wp;   wp += (size_t)128*C*2*sizeof(float);  // 128 KB
  float*  AB0  = (float*)wp;   wp += (size_t)2*C*sizeof(float);
  float*  AB1  = (float*)wp;   wp += (size_t)2*C*sizeof(float);
  float*  w1t  = (float*)wp;   wp += (size_t)C*C*sizeof(float);      // 64 KB

  float* out_xyz  = (float*)d_out;            // [B,S,3]
  float* out_feat = (float*)d_out + B*S*3;    // [B,S,C]

  prep_kernel<<<(B*N)/256, 256, 0, stream>>>(xyz, pts4);
  transpose_w1_kernel<<<(C*C)/256, 256, 0, stream>>>(w1, w1t);
  fps_kernel<<<B, 256, 0, stream>>>(pts4, q4, out_xyz);
  knn_kernel<<<(B*S*64)/256, 256, 0, stream>>>(pts4, q4, knn);
  gemm0_kernel<<<R/256, 256, 0, stream>>>(pts4, q4, features, knn, w0, b0, Z);
  stats_kernel<<<128, 256, 0, stream>>>(Z, part);
  finalize_kernel<<<1, 128, 0, stream>>>(part, g0, be0, AB0);
  gemm1_kernel<<<R/64, 256, 0, stream>>>(Z, AB0, w1t, b1);
  stats_kernel<<<128, 256, 0, stream>>>(Z, part);
  finalize_kernel<<<1, 128, 0, stream>>>(part, g1, be1, AB1);
  maxpool_kernel<<<(B*S*32)/256, 256, 0, stream>>>(Z, AB1, out_feat);
}